// Round 5
// baseline (1284.333 us; speedup 1.0000x reference)
//
#include <hip/hip_runtime.h>
#include <hip/hip_bf16.h>

#define NUM_STEPS 10
#define DT 0.1f
#define BK 64

typedef __bf16 bf16_t;
typedef __bf16 bf16x8 __attribute__((ext_vector_type(8)));
typedef __bf16 bf16x4 __attribute__((ext_vector_type(4)));
typedef float f32x4 __attribute__((ext_vector_type(4)));

// async global->LDS, 16B per lane; LDS dst is wave-uniform base + lane*16
__device__ __forceinline__ void async16(const bf16_t* g, bf16_t* l) {
  __builtin_amdgcn_global_load_lds(
      (const __attribute__((address_space(1))) void*)g,
      (__attribute__((address_space(3))) void*)l, 16, 0, 0);
}

__global__ void cvt_f32_to_bf16(const float* __restrict__ in,
                                bf16_t* __restrict__ out, int n4) {
  int i = blockIdx.x * blockDim.x + threadIdx.x;
  if (i < n4) {
    float4 v = ((const float4*)in)[i];
    bf16x4 o = {(bf16_t)v.x, (bf16_t)v.y, (bf16_t)v.z, (bf16_t)v.w};
    ((bf16x4*)out)[i] = o;
  }
}

__global__ void init_h(const float* __restrict__ h0, float* __restrict__ hout,
                       bf16_t* __restrict__ hb, int n4) {
  int i = blockIdx.x * blockDim.x + threadIdx.x;
  if (i < n4) {
    float4 v = ((const float4*)h0)[i];
    ((float4*)hout)[i] = v;
    bf16x4 o = {(bf16_t)v.x, (bf16_t)v.y, (bf16_t)v.z, (bf16_t)v.w};
    ((bf16x4*)hb)[i] = o;
  }
}

// C[M,N] = A[M,K] * B[N,K]^T   (NT, both row-major, K contiguous)
// 128x64 tile, 256 threads (4 waves), grid 1024 blocks -> 4 blocks/CU:
// 4 independent barrier groups per CU cover each other's vmcnt drains
// (m97@4096's concurrency profile; groups -- not waves -- hide the drain).
// K-loop & epilogue logic otherwise identical to round 3 (verified:
// 0 bank conflicts, WRITE_SIZE == logical bytes, absmax 0.0156).
// EPI=0: out_ihb(bf16) = acc + bias1[col] + bias2[col]
// EPI=1: pre = acc + ihb; h_io = d*h_io + (1-d)*tanh(pre) [fp32 carry];
//        hb_next = bf16(h_io)
template <int EPI>
__global__ __launch_bounds__(256, 4) void gemm_nt(
    const bf16_t* __restrict__ A, const bf16_t* __restrict__ Bw, int M, int N,
    int K, const float* __restrict__ bias1, const float* __restrict__ bias2,
    bf16_t* __restrict__ out_ihb, const bf16_t* __restrict__ ihb,
    const float* __restrict__ tau, float* __restrict__ h_io,
    bf16_t* __restrict__ hb_next) {
  __shared__ __align__(16) bf16_t As[128 * BK];  // 16 KB
  __shared__ __align__(16) bf16_t Bs[64 * BK];   // 8 KB

  const int tid = threadIdx.x;
  const int lane = tid & 63;
  const int wave = tid >> 6;     // 0..3
  const int waveM = wave >> 1;   // 0..1  (64-row half of 128)
  const int waveN = wave & 1;    // 0..1  (32-col half of 64)

  // XCD swizzle: 16x8 tile sub-grid per XCD (verified technique, r2-r4)
  const int lin = blockIdx.y * gridDim.x + blockIdx.x;  // 0..1023
  const int xcd = lin & 7;
  const int slot = lin >> 3;                   // 0..127
  const int bx = (xcd & 1) * 16 + (slot & 15); // 0..31
  const int by = (xcd >> 1) * 8 + (slot >> 4); // 0..31
  const long bRow = (long)by * 128;
  const long bCol = (long)bx * 64;

  // staging lane map: row = lane&15 in a 16-row group, kcol = (lane>>4)*8
  // in a 32-col k-slice; one async16 writes one contiguous 1 KB LDS chunk
  const int laneRow = lane & 15;
  const int laneK = (lane >> 4) << 3;
  // wave w stages A rows [w*32, w*32+32) (2 rowgroups) and B rows
  // [w*16, w*16+16) (1 rowgroup), each x 2 kslices: 6 async16/wave/iter
  const bf16_t* aG = A + (bRow + wave * 32 + laneRow) * (long)K + laneK;
  const bf16_t* bG = Bw + (bCol + wave * 16 + laneRow) * (long)K + laneK;

  f32x4 acc[4][2] = {};

  for (int k0 = 0; k0 < K; k0 += BK) {
#pragma unroll
    for (int r = 0; r < 2; ++r)
#pragma unroll
      for (int ks = 0; ks < 2; ++ks)
        async16(aG + (long)r * 16 * K + k0 + ks * 32,
                &As[((wave * 2 + r) * 2 + ks) * 512]);
#pragma unroll
    for (int ks = 0; ks < 2; ++ks)
      async16(bG + k0 + ks * 32, &Bs[(wave * 2 + ks) * 512]);
    __syncthreads();  // compiler emits the vmcnt drain before s_barrier

#pragma unroll
    for (int ks = 0; ks < 2; ++ks) {
      bf16x8 aF[4], bF[2];
#pragma unroll
      for (int t = 0; t < 4; ++t)
        aF[t] = *(const bf16x8*)&As[((waveM * 4 + t) * 2 + ks) * 512 + lane * 8];
#pragma unroll
      for (int u = 0; u < 2; ++u)
        bF[u] = *(const bf16x8*)&Bs[((waveN * 2 + u) * 2 + ks) * 512 + lane * 8];
#pragma unroll
      for (int t = 0; t < 4; ++t)
#pragma unroll
        for (int u = 0; u < 2; ++u)
          acc[t][u] = __builtin_amdgcn_mfma_f32_16x16x32_bf16(
              aF[t], bF[u], acc[t][u], 0, 0, 0);
    }
    __syncthreads();
  }

  // C/D layout: col = lane&15, row = (lane>>4)*4 + reg   [measured m89/m91]
  const int eRow = (lane >> 4) << 2;
  const int eCol = lane & 15;

  if (EPI == 0) {
#pragma unroll
    for (int u = 0; u < 2; ++u) {
      const int col = (int)bCol + waveN * 32 + u * 16 + eCol;
      const float bb = bias1[col] + bias2[col];
#pragma unroll
      for (int t = 0; t < 4; ++t) {
        const long row = bRow + waveM * 64 + t * 16 + eRow;
#pragma unroll
        for (int r = 0; r < 4; ++r)
          out_ihb[(row + r) * N + col] = (bf16_t)(acc[t][u][r] + bb);
      }
    }
  } else {
#pragma unroll
    for (int u = 0; u < 2; ++u) {
      const int col = (int)bCol + waveN * 32 + u * 16 + eCol;
      const float dcy = __expf(-DT / tau[col]);
#pragma unroll
      for (int t = 0; t < 4; ++t) {
        const long row = bRow + waveM * 64 + t * 16 + eRow;
#pragma unroll
        for (int r = 0; r < 4; ++r) {
          const long idx = (row + r) * N + col;
          float pre = acc[t][u][r] + (float)ihb[idx];
          float th = tanhf(pre);
          float hn = dcy * h_io[idx] + (1.0f - dcy) * th;
          h_io[idx] = hn;
          hb_next[idx] = (bf16_t)hn;
        }
      }
    }
  }
}

extern "C" void kernel_launch(void* const* d_in, const int* in_sizes, int n_in,
                              void* d_out, int out_size, void* d_ws,
                              size_t ws_size, hipStream_t stream) {
  const float* x = (const float*)d_in[0];
  const float* h0 = (const float*)d_in[1];
  const float* W_ih = (const float*)d_in[2];
  const float* b_ih = (const float*)d_in[3];
  const float* W_hh = (const float*)d_in[4];
  const float* b_hh = (const float*)d_in[5];
  const float* tau = (const float*)d_in[6];
  float* hout = (float*)d_out;

  const int B = 4096, I = 1024, H = 2048;

  char* ws = (char*)d_ws;
  bf16_t* ihb = (bf16_t*)ws; ws += (size_t)B * H * 2;   // 16 MB
  bf16_t* hb0 = (bf16_t*)ws; ws += (size_t)B * H * 2;   // 16 MB
  bf16_t* hb1 = (bf16_t*)ws; ws += (size_t)B * H * 2;   // 16 MB
  bf16_t* xb = (bf16_t*)ws;  ws += (size_t)B * I * 2;   // 8 MB
  bf16_t* wihb = (bf16_t*)ws; ws += (size_t)H * I * 2;  // 4 MB
  bf16_t* whhb = (bf16_t*)ws; ws += (size_t)H * H * 2;  // 8 MB

  cvt_f32_to_bf16<<<(B * I / 4 + 255) / 256, 256, 0, stream>>>(x, xb, B * I / 4);
  cvt_f32_to_bf16<<<(H * I / 4 + 255) / 256, 256, 0, stream>>>(W_ih, wihb, H * I / 4);
  cvt_f32_to_bf16<<<(H * H / 4 + 255) / 256, 256, 0, stream>>>(W_hh, whhb, H * H / 4);
  init_h<<<(B * H / 4 + 255) / 256, 256, 0, stream>>>(h0, hout, hb0, B * H / 4);

  dim3 grid(H / 64, B / 128);  // (32, 32) = 1024 blocks -> 4 blocks/CU
  // ihb = x @ W_ih^T + b_ih + b_hh   (fold both biases once, store bf16)
  gemm_nt<0><<<grid, 256, 0, stream>>>(xb, wihb, B, H, I, b_ih, b_hh, ihb,
                                       nullptr, nullptr, nullptr, nullptr);

  bf16_t* hb[2] = {hb0, hb1};
  for (int s = 0; s < NUM_STEPS; ++s) {
    gemm_nt<1><<<grid, 256, 0, stream>>>(hb[s & 1], whhb, B, H, H, nullptr,
                                         nullptr, nullptr, ihb, tau, hout,
                                         hb[(s + 1) & 1]);
  }
}

// Round 6
// 968.381 us; speedup vs baseline: 1.3263x; 1.3263x over previous
//
#include <hip/hip_runtime.h>
#include <hip/hip_bf16.h>

#define NUM_STEPS 10
#define DT 0.1f
#define BK 64

typedef __bf16 bf16_t;
typedef __bf16 bf16x8 __attribute__((ext_vector_type(8)));
typedef __bf16 bf16x4 __attribute__((ext_vector_type(4)));
typedef float f32x4 __attribute__((ext_vector_type(4)));

// async global->LDS, 16B per lane; LDS dst is wave-uniform base + lane*16
__device__ __forceinline__ void async16(const bf16_t* g, bf16_t* l) {
  __builtin_amdgcn_global_load_lds(
      (const __attribute__((address_space(1))) void*)g,
      (__attribute__((address_space(3))) void*)l, 16, 0, 0);
}

__global__ void cvt_f32_to_bf16(const float* __restrict__ in,
                                bf16_t* __restrict__ out, int n4) {
  int i = blockIdx.x * blockDim.x + threadIdx.x;
  if (i < n4) {
    float4 v = ((const float4*)in)[i];
    bf16x4 o = {(bf16_t)v.x, (bf16_t)v.y, (bf16_t)v.z, (bf16_t)v.w};
    ((bf16x4*)out)[i] = o;
  }
}

// out[H][B] = transpose(in[B][H]);  H=2048, B=4096; 32x32 LDS tiles
__global__ void transpose_f32(const float* __restrict__ in,
                              float* __restrict__ out) {
  __shared__ float t[32][33];
  const int c0 = blockIdx.x * 32;  // H index
  const int r0 = blockIdx.y * 32;  // B index
  const int tx = threadIdx.x & 31;
  const int ty = threadIdx.x >> 5;  // 0..7
#pragma unroll
  for (int j = 0; j < 32; j += 8)
    t[ty + j][tx] = in[(long)(r0 + ty + j) * 2048 + c0 + tx];
  __syncthreads();
#pragma unroll
  for (int j = 0; j < 32; j += 8)
    out[(long)(c0 + ty + j) * 4096 + r0 + tx] = t[tx][ty + j];
}

// C[M,N] = A[M,K] * B[N,K]^T   (NT, both row-major, K contiguous)
// R3 base (best known: 512 thr, 128x128 tile, BK=64, 0 bank conflicts) plus:
//  - phase stagger: second-sweep blocks s_sleep ~3300cyc so the two
//    co-resident blocks on a CU anti-phase their stage bursts
//  - transposed epilogue buffers ihbT/hT [H][B]: r-loop becomes contiguous
// EPI=0: ihbT[col][row] = acc + bias1[col] + bias2[col]        (bf16x4 stores)
// EPI=1: pre = acc + ihbT; hn = d*hT + (1-d)*tanh(pre); hT = hn (float4);
//        hb_next[row][col] = bf16(hn) (scatter);  last step: out[row][col]=hn
template <int EPI>
__global__ __launch_bounds__(512, 4) void gemm_nt(
    const bf16_t* __restrict__ A, const bf16_t* __restrict__ Bw, int M, int N,
    int K, const float* __restrict__ bias1, const float* __restrict__ bias2,
    bf16_t* __restrict__ ihbT_out, const bf16_t* __restrict__ ihbT,
    const float* __restrict__ tau, float* __restrict__ hT,
    bf16_t* __restrict__ hb_next, float* __restrict__ out, int writeOut) {
  __shared__ __align__(16) bf16_t As[128 * BK];  // 16 KB
  __shared__ __align__(16) bf16_t Bs[128 * BK];  // 16 KB

  const int tid = threadIdx.x;
  const int lane = tid & 63;
  const int wave = tid >> 6;     // 0..7
  const int waveM = wave >> 2;   // 0..1  (64-row half)
  const int waveN = wave & 3;    // 0..3  (32-col quarter)

  // XCD swizzle (verified: FETCH 135->82 MB): 8x8 tile sub-grid per XCD
  const int lin = blockIdx.y * gridDim.x + blockIdx.x;  // 0..511
  const int xcd = lin & 7;
  const int slot = lin >> 3;                   // 0..63
  const int bx = (xcd & 1) * 8 + (slot & 7);   // 0..15
  const int by = (xcd >> 1) * 8 + (slot >> 3); // 0..31
  const long bRow = (long)by * 128;
  const long bCol = (long)bx * 128;

  // Phase stagger: with round-robin dispatch, slots s and s+32 of an XCD
  // land on the same CU; delay the second sweep ~half an iteration so the
  // pair's stage bursts interleave instead of colliding.
  if (slot & 32) __builtin_amdgcn_s_sleep(52);

  // staging: wave w covers rows [w*16, w*16+16); lane -> row = lane&15,
  // kcol = (lane>>4)*8; one async16 writes one contiguous 1 KB LDS chunk
  const int laneRow = lane & 15;
  const int laneK = (lane >> 4) << 3;
  const bf16_t* aG = A + (bRow + wave * 16 + laneRow) * (long)K + laneK;
  const bf16_t* bG = Bw + (bCol + wave * 16 + laneRow) * (long)K + laneK;
  bf16_t* aL0 = &As[(wave * 2 + 0) * 512];
  bf16_t* aL1 = &As[(wave * 2 + 1) * 512];
  bf16_t* bL0 = &Bs[(wave * 2 + 0) * 512];
  bf16_t* bL1 = &Bs[(wave * 2 + 1) * 512];

  f32x4 acc[4][2] = {};

  for (int k0 = 0; k0 < K; k0 += BK) {
    async16(aG + k0, aL0);
    async16(aG + k0 + 32, aL1);
    async16(bG + k0, bL0);
    async16(bG + k0 + 32, bL1);
    __syncthreads();  // compiler emits the vmcnt drain before s_barrier

#pragma unroll
    for (int ks = 0; ks < 2; ++ks) {
      bf16x8 aF[4], bF[2];
#pragma unroll
      for (int t = 0; t < 4; ++t)
        aF[t] = *(const bf16x8*)&As[((waveM * 4 + t) * 2 + ks) * 512 + lane * 8];
#pragma unroll
      for (int u = 0; u < 2; ++u)
        bF[u] = *(const bf16x8*)&Bs[((waveN * 2 + u) * 2 + ks) * 512 + lane * 8];
#pragma unroll
      for (int t = 0; t < 4; ++t)
#pragma unroll
        for (int u = 0; u < 2; ++u)
          acc[t][u] = __builtin_amdgcn_mfma_f32_16x16x32_bf16(
              aF[t], bF[u], acc[t][u], 0, 0, 0);
    }
    __syncthreads();
  }

  // C/D layout: col = lane&15, row = (lane>>4)*4 + reg   [measured m89/m91]
  const int eRow = (lane >> 4) << 2;
  const int eCol = lane & 15;

  if (EPI == 0) {
#pragma unroll
    for (int u = 0; u < 2; ++u) {
      const int col = (int)bCol + waveN * 32 + u * 16 + eCol;
      const float bb = bias1[col] + bias2[col];
#pragma unroll
      for (int t = 0; t < 4; ++t) {
        const long row = bRow + waveM * 64 + t * 16 + eRow;
        const long iT = (long)col * M + row;
        bf16x4 o;
#pragma unroll
        for (int r = 0; r < 4; ++r) o[r] = (bf16_t)(acc[t][u][r] + bb);
        *(bf16x4*)&ihbT_out[iT] = o;
      }
    }
  } else {
#pragma unroll
    for (int u = 0; u < 2; ++u) {
      const int col = (int)bCol + waveN * 32 + u * 16 + eCol;
      const float dcy = __expf(-DT / tau[col]);
#pragma unroll
      for (int t = 0; t < 4; ++t) {
        const long row = bRow + waveM * 64 + t * 16 + eRow;
        const long iT = (long)col * M + row;
        const f32x4 hp = *(const f32x4*)&hT[iT];
        const bf16x4 ih4 = *(const bf16x4*)&ihbT[iT];
        float hn[4];
#pragma unroll
        for (int r = 0; r < 4; ++r) {
          const float pre = acc[t][u][r] + (float)ih4[r];
          const float th = tanhf(pre);
          hn[r] = dcy * hp[r] + (1.0f - dcy) * th;
        }
        if (!writeOut) {
          f32x4 hv = {hn[0], hn[1], hn[2], hn[3]};
          *(f32x4*)&hT[iT] = hv;
#pragma unroll
          for (int r = 0; r < 4; ++r)
            hb_next[(row + r) * (long)N + col] = (bf16_t)hn[r];
        } else {
#pragma unroll
          for (int r = 0; r < 4; ++r)
            out[(row + r) * (long)N + col] = hn[r];
        }
      }
    }
  }
}

extern "C" void kernel_launch(void* const* d_in, const int* in_sizes, int n_in,
                              void* d_out, int out_size, void* d_ws,
                              size_t ws_size, hipStream_t stream) {
  const float* x = (const float*)d_in[0];
  const float* h0 = (const float*)d_in[1];
  const float* W_ih = (const float*)d_in[2];
  const float* b_ih = (const float*)d_in[3];
  const float* W_hh = (const float*)d_in[4];
  const float* b_hh = (const float*)d_in[5];
  const float* tau = (const float*)d_in[6];
  float* hout = (float*)d_out;

  const int B = 4096, I = 1024, H = 2048;

  char* ws = (char*)d_ws;
  bf16_t* ihbT = (bf16_t*)ws; ws += (size_t)B * H * 2;  // 16 MB  [H][B]
  float* hT = (float*)ws;     ws += (size_t)B * H * 4;  // 32 MB  [H][B]
  bf16_t* hb0 = (bf16_t*)ws;  ws += (size_t)B * H * 2;  // 16 MB  [B][H]
  bf16_t* hb1 = (bf16_t*)ws;  ws += (size_t)B * H * 2;  // 16 MB  [B][H]
  bf16_t* xb = (bf16_t*)ws;   ws += (size_t)B * I * 2;  // 8 MB
  bf16_t* wihb = (bf16_t*)ws; ws += (size_t)H * I * 2;  // 4 MB
  bf16_t* whhb = (bf16_t*)ws; ws += (size_t)H * H * 2;  // 8 MB

  cvt_f32_to_bf16<<<(B * I / 4 + 255) / 256, 256, 0, stream>>>(x, xb, B * I / 4);
  cvt_f32_to_bf16<<<(H * I / 4 + 255) / 256, 256, 0, stream>>>(W_ih, wihb, H * I / 4);
  cvt_f32_to_bf16<<<(H * H / 4 + 255) / 256, 256, 0, stream>>>(W_hh, whhb, H * H / 4);
  cvt_f32_to_bf16<<<(B * H / 4 + 255) / 256, 256, 0, stream>>>(h0, hb0, B * H / 4);
  transpose_f32<<<dim3(H / 32, B / 32), 256, 0, stream>>>(h0, hT);

  dim3 grid(H / 128, B / 128);  // (16, 32) = 512 blocks, 2/CU
  // ihbT = (x @ W_ih^T + b_ih + b_hh)^T   (fold both biases once, bf16)
  gemm_nt<0><<<grid, 512, 0, stream>>>(xb, wihb, B, H, I, b_ih, b_hh, ihbT,
                                       nullptr, nullptr, nullptr, nullptr,
                                       nullptr, 0);

  bf16_t* hb[2] = {hb0, hb1};
  for (int s = 0; s < NUM_STEPS; ++s) {
    gemm_nt<1><<<grid, 512, 0, stream>>>(
        hb[s & 1], whhb, B, H, H, nullptr, nullptr, nullptr, ihbT, tau, hT,
        hb[(s + 1) & 1], hout, (s == NUM_STEPS - 1) ? 1 : 0);
  }
}